// Round 3
// baseline (1301544.336 us; speedup 1.0000x reference)
//
#include <hip/hip_runtime.h>
#include <stdint.h>

// RNN-T greedy decode v3: SPMD persistent blocks, fence-free LLC mailboxes.
// 160 blocks x 512 threads, each block owns 4 LSTM units (16 Wh cols),
// 4 Wpred cols, 6-7 Wout cols. Per step (5000, sequential):
//   phaseA: commit prev decision, gates=Gc+lut[last], pointwise -> publish h (F1)
//   pred  : tanh(encT + h@Wpred cols) -> publish (F2)   [split-K x16 per row]
//   Wh    : speculative h@Wh partials (overlaps sync windows)
//   out   : logits cols + per-block candidate -> publish (F3)
//   decide: blocks 0..31 reduce 160 candidates for row r -> sym/emit/last (F4)
// Data moves via LLC only: relaxed agent atomic stores + sc0/sc1 bypass loads.
// Weights/lut/encT are read with NORMAL cached loads (never invalidated).

typedef unsigned int u32;
typedef unsigned long long u64;
typedef float f4 __attribute__((ext_vector_type(4)));

constexpr int NB = 160, TPB = 512;

// ---- static device scratch ----
__device__ float g_encT[1000 * 32 * 640];   // enc@Wenc + b_joint  [T][B][J]
__device__ float g_lut[1025 * 2560];        // embed@Wx + b_lstm (row 1024 = b_lstm)
__device__ float g_WhT[2560 * 640];         // Wh^T   [col][k]
__device__ float g_WpT[640 * 640];          // Wpred^T[col][k]
__device__ float g_WoT[1025 * 640];         // Wout^T [col][k]
__device__ float g_h[2 * 32 * 640];         // h_new, parity slots
__device__ float g_t[2 * 32 * 640];         // tanh joint vec, parity slots
__device__ double g_cval[2 * 32 * 160];     // per-block candidate value
__device__ int    g_cidx[2 * 32 * 160];     // per-block candidate index
__device__ u32    g_sym[2 * 32];            // decision word: emit | (last<<1)
__device__ u32    g_cnt[64 * 32];           // counters, 128B apart

constexpr int F1L = 0,  F1R = 10;   // 10 leaves x16 blocks
constexpr int F2L = 11, F2R = 21;
constexpr int F3L = 22, F3R = 32;
constexpr int F4L = 33, F4R = 37;   // 4 leaves x8 deciders

__device__ __forceinline__ float sigmf(float x) { return 1.0f / (1.0f + expf(-x)); }

__device__ __forceinline__ void bump(int leaf, int root, u32 per_leaf, int step) {
  u32 old = __hip_atomic_fetch_add(&g_cnt[leaf * 32], 1u, __ATOMIC_RELAXED, __HIP_MEMORY_SCOPE_AGENT);
  if (old + 1u == (u32)(step + 1) * per_leaf)
    __hip_atomic_fetch_add(&g_cnt[root * 32], 1u, __ATOMIC_RELAXED, __HIP_MEMORY_SCOPE_AGENT);
}

__device__ __forceinline__ void waitroot(int root, u32 target) {
  if (threadIdx.x == 0) {
    while (__hip_atomic_load(&g_cnt[root * 32], __ATOMIC_RELAXED, __HIP_MEMORY_SCOPE_AGENT) < target)
      __builtin_amdgcn_s_sleep(1);
  }
  __syncthreads();
  asm volatile("" ::: "memory");
}

// 40 contiguous floats via 10 cache-bypassing dwordx4 loads, one vmcnt drain.
__device__ __forceinline__ void load40(const float* p, float* r) {
  f4 t[10];
#pragma unroll
  for (int i = 0; i < 10; i++)
    asm volatile("global_load_dwordx4 %0, %1, off sc0 sc1" : "=v"(t[i]) : "v"(p + 4 * i));
  asm volatile("s_waitcnt vmcnt(0)"
               : "+v"(t[0]), "+v"(t[1]), "+v"(t[2]), "+v"(t[3]), "+v"(t[4]),
                 "+v"(t[5]), "+v"(t[6]), "+v"(t[7]), "+v"(t[8]), "+v"(t[9]));
#pragma unroll
  for (int i = 0; i < 10; i++) {
    r[4 * i + 0] = t[i].x; r[4 * i + 1] = t[i].y;
    r[4 * i + 2] = t[i].z; r[4 * i + 3] = t[i].w;
  }
}

// ---------------- precompute: LUT = embed @ Wx + b_lstm (row 1024 = b_lstm) ----------
__global__ __launch_bounds__(256) void k_lut(const float* __restrict__ embed,
                                             const float* __restrict__ Wx,
                                             const float* __restrict__ b_lstm) {
  const int tid = threadIdx.x;
  const int cg = blockIdx.x % 10, rg = blockIdx.x / 10;  // rg 0..128
  const int c = cg * 256 + tid;
  const int r0 = rg * 8;
  double acc[8];
  double bl = (double)b_lstm[c];
#pragma unroll
  for (int i = 0; i < 8; i++) acc[i] = bl;
  for (int e = 0; e < 640; e++) {
    double wx = (double)Wx[(size_t)e * 2560 + c];
#pragma unroll
    for (int i = 0; i < 8; i++) {
      int r = r0 + i;
      if (r < 1024) acc[i] += (double)embed[(size_t)r * 640 + e] * wx;
    }
  }
#pragma unroll
  for (int i = 0; i < 8; i++) {
    int r = r0 + i;
    if (r < 1025) g_lut[(size_t)r * 2560 + c] = (float)acc[i];
  }
  if (blockIdx.x == 0) {  // re-init counters every call
    for (int i = tid; i < 64 * 32; i += 256) g_cnt[i] = 0u;
  }
}

// ---------- precompute: encT[t][b][j] = sum_d enc[b][d][t]*Wenc[d][j] + b_joint[j] ----
__global__ __launch_bounds__(256) void k_encproj(const float* __restrict__ enc,
                                                 const float* __restrict__ Wenc,
                                                 const float* __restrict__ bj) {
  __shared__ __align__(16) float As[16][68];
  __shared__ __align__(16) float Bs[16][68];
  const int tid = threadIdx.x;
  const int jt = blockIdx.x % 10, tt = blockIdx.x / 10;
  const int b = blockIdx.y;
  const int t0 = tt * 64, j0 = jt * 64;
  const int ty = tid >> 4, tx = tid & 15;
  double acc[4][4] = {};
  const float* Ab = enc + (size_t)b * 640 * 1000;
  for (int d0 = 0; d0 < 640; d0 += 16) {
#pragma unroll
    for (int i = 0; i < 4; i++) {
      int idx = tid + i * 256;
      int d = idx >> 6, t = idx & 63;
      As[d][t] = (t0 + t < 1000) ? Ab[(size_t)(d0 + d) * 1000 + t0 + t] : 0.f;
      Bs[d][t] = Wenc[(size_t)(d0 + d) * 640 + j0 + t];
    }
    __syncthreads();
#pragma unroll
    for (int kk = 0; kk < 16; kk++) {
      float a0 = As[kk][ty * 4 + 0], a1 = As[kk][ty * 4 + 1];
      float a2 = As[kk][ty * 4 + 2], a3 = As[kk][ty * 4 + 3];
      float b0 = Bs[kk][tx * 4 + 0], b1 = Bs[kk][tx * 4 + 1];
      float b2 = Bs[kk][tx * 4 + 2], b3 = Bs[kk][tx * 4 + 3];
      float aa[4] = {a0, a1, a2, a3}, bb[4] = {b0, b1, b2, b3};
#pragma unroll
      for (int i = 0; i < 4; i++)
#pragma unroll
        for (int j = 0; j < 4; j++) acc[i][j] += (double)aa[i] * (double)bb[j];
    }
    __syncthreads();
  }
#pragma unroll
  for (int i = 0; i < 4; i++) {
    int t = t0 + ty * 4 + i;
    if (t < 1000)
#pragma unroll
      for (int j = 0; j < 4; j++)
        g_encT[(size_t)t * 20480 + b * 640 + j0 + tx * 4 + j] =
            (float)(acc[i][j] + (double)bj[j0 + tx * 4 + j]);
  }
}

// ---------------- precompute: transpose Wh, Wpred, Wout to [col][k] -----------------
__global__ __launch_bounds__(256) void k_tr(const float* __restrict__ Wh,
                                            const float* __restrict__ Wp,
                                            const float* __restrict__ Wo) {
  int i = blockIdx.x * 256 + threadIdx.x;
  if (i < 2560 * 640) {
    int col = i / 640, k = i - col * 640;
    g_WhT[i] = Wh[(size_t)k * 2560 + col];
  }
  int j = i - 2560 * 640;
  if (j >= 0 && j < 640 * 640) {
    int col = j / 640, k = j - col * 640;
    g_WpT[j] = Wp[(size_t)k * 640 + col];
  }
  int l = i - 2560 * 640 - 640 * 640;
  if (l >= 0 && l < 1025 * 640) {
    int col = l / 640, k = l - col * 640;
    g_WoT[l] = Wo[(size_t)k * 1025 + col];
  }
}

// ------------------------------- persistent decode ----------------------------------
__global__ __launch_bounds__(512, 2) void k_decode(float* __restrict__ out,
                                                   const int* __restrict__ lens,
                                                   const float* __restrict__ b_out) {
  __shared__ double s_dv[8];
  __shared__ int s_di[8];

  const int tid = threadIdx.x;
  const int bid = blockIdx.x;
  const int b = tid >> 4;          // row 0..31
  const int c0 = tid & 15;         // k-slice / col index 0..15
  const int u0 = 4 * bid;          // 4 LSTM units
  const int j0 = 4 * bid;          // 4 Wpred cols
  const int nout = (bid < 65) ? 7 : 6;
  const int wc0 = (bid < 65) ? 7 * bid : 6 * bid + 65;   // Wout col range (covers 0..1024)
  const int gg = c0 >> 2;          // gate index for phase A (col = gg*640 + u0 + (c0&3))

  double bod[7];
#pragma unroll
  for (int m = 0; m < 7; m++) bod[m] = (m < nout) ? (double)b_out[wc0 + m] : 0.0;

  // persistent state
  double Gc[16];                   // committed h@Wh totals (all lanes hold all 16 cols)
  double Ga[16];                   // per-k-slice speculative partials
#pragma unroll
  for (int i = 0; i < 16; i++) { Gc[i] = 0.0; Ga[i] = 0.0; }
  double cst = 0.0, cn_pend = 0.0;
  float hst = 0.f, hn_pend = 0.f;
  int lastb = 1024;
  // decider state (thread 0 of blocks 0..31)
  int lenr = 0, alive = 0, lastr = 1024;
  if (bid < 32 && tid == 0) lenr = lens[bid];
  int tcur = 0, scur = 0;

  for (int step = 0; step < 5000; step++) {
    const int slot = step & 1;

    // ================= phase A: commit prev decision, gates, publish h ==============
    if (step > 0) {
      waitroot(F4R, (u32)step * 4u);
      u32 w = 0;
      if ((tid & 15) == 0)
        w = __hip_atomic_load(&g_sym[(slot ^ 1) * 32 + b], __ATOMIC_RELAXED, __HIP_MEMORY_SCOPE_AGENT);
      w = __shfl(w, (tid & 63) & 48, 64);
      int emit = (int)(w & 1u);
      lastb = (int)(w >> 1);
      // combine speculative partials across the 16 k-slice lanes
#pragma unroll
      for (int mm = 1; mm < 16; mm <<= 1)
#pragma unroll
        for (int i = 0; i < 16; i++) Ga[i] += __shfl_xor(Ga[i], mm, 64);
      if (emit) {
#pragma unroll
        for (int i = 0; i < 16; i++) Gc[i] = Ga[i];
        cst = cn_pend; hst = hn_pend;
      }
    }
    double pre = Gc[c0] +
        (double)g_lut[(size_t)lastb * 2560 + (size_t)gg * 640 + u0 + (c0 & 3)];
    double q1 = __shfl_xor(pre, 4, 64);
    double q2 = __shfl_xor(pre, 8, 64);
    double q3 = __shfl_xor(q1, 8, 64);
    double di_ = gg == 0 ? pre : gg == 1 ? q1 : gg == 2 ? q2 : q3;
    double df_ = gg == 0 ? q1 : gg == 1 ? pre : gg == 2 ? q3 : q2;
    double dg_ = gg == 0 ? q2 : gg == 1 ? q3 : gg == 2 ? pre : q1;
    double do_ = gg == 0 ? q3 : gg == 1 ? q2 : gg == 2 ? q1 : pre;
    cn_pend = (double)sigmf((float)df_) * cst +
              (double)sigmf((float)di_) * (double)tanhf((float)dg_);
    hn_pend = sigmf((float)do_) * tanhf((float)cn_pend);
    if (c0 < 4)
      __hip_atomic_store(&g_h[slot * 20480 + b * 640 + u0 + c0], hn_pend,
                         __ATOMIC_RELAXED, __HIP_MEMORY_SCOPE_AGENT);
    __syncthreads();
    if (tid == 0) bump(F1L + (bid >> 4), F1R, 16u, step);

    // encT prefetch (normal cached load, in flight during F1 wait)
    float encv = 0.f;
    if (c0 < 4) encv = g_encT[(size_t)tcur * 20480 + b * 640 + j0 + c0];

    // ================= load h slice, pred dot =====================================
    waitroot(F1R, (u32)(step + 1) * 10u);
    float a[40];
    load40(g_h + slot * 20480 + b * 640 + 40 * c0, a);

    double pa[4] = {0.0, 0.0, 0.0, 0.0};
    {
      const float* wp = g_WpT + (size_t)j0 * 640 + 40 * c0;
#pragma unroll
      for (int i = 0; i < 10; i++) {
#pragma unroll
        for (int jj = 0; jj < 4; jj++) {
          f4 w = *(const f4*)(wp + (size_t)jj * 640 + 4 * i);
          pa[jj] += (double)a[4 * i + 0] * (double)w.x + (double)a[4 * i + 1] * (double)w.y +
                    (double)a[4 * i + 2] * (double)w.z + (double)a[4 * i + 3] * (double)w.w;
        }
      }
    }
#pragma unroll
    for (int mm = 1; mm < 16; mm <<= 1)
#pragma unroll
      for (int jj = 0; jj < 4; jj++) pa[jj] += __shfl_xor(pa[jj], mm, 64);
    if (c0 < 4) {
      float tv = tanhf((float)((double)encv + pa[c0]));
      __hip_atomic_store(&g_t[slot * 20480 + b * 640 + j0 + c0], tv,
                         __ATOMIC_RELAXED, __HIP_MEMORY_SCOPE_AGENT);
    }
    __syncthreads();
    if (tid == 0) bump(F2L + (bid >> 4), F2R, 16u, step);

    // ================= speculative Wh partials (hides F2 propagation) =============
#pragma unroll
    for (int ci = 0; ci < 16; ci++) {
      const float* wh = g_WhT + (size_t)((ci >> 2) * 640 + u0 + (ci & 3)) * 640 + 40 * c0;
      double acc = 0.0;
#pragma unroll
      for (int i = 0; i < 10; i++) {
        f4 w = *(const f4*)(wh + 4 * i);
        acc += (double)a[4 * i + 0] * (double)w.x + (double)a[4 * i + 1] * (double)w.y +
               (double)a[4 * i + 2] * (double)w.z + (double)a[4 * i + 3] * (double)w.w;
      }
      Ga[ci] = acc;
    }

    // ================= load tanh slice, out dots, candidate =======================
    waitroot(F2R, (u32)(step + 1) * 10u);
    float tt[40];
    load40(g_t + slot * 20480 + b * 640 + 40 * c0, tt);

    double oa[7];
#pragma unroll
    for (int m = 0; m < 7; m++) oa[m] = 0.0;
#pragma unroll
    for (int m = 0; m < 7; m++) {
      if (m < nout) {
        const float* wo = g_WoT + (size_t)(wc0 + m) * 640 + 40 * c0;
        double acc = 0.0;
#pragma unroll
        for (int i = 0; i < 10; i++) {
          f4 w = *(const f4*)(wo + 4 * i);
          acc += (double)tt[4 * i + 0] * (double)w.x + (double)tt[4 * i + 1] * (double)w.y +
                 (double)tt[4 * i + 2] * (double)w.z + (double)tt[4 * i + 3] * (double)w.w;
        }
        oa[m] = acc;
      }
    }
#pragma unroll
    for (int mm = 1; mm < 16; mm <<= 1)
#pragma unroll
      for (int m = 0; m < 7; m++) oa[m] += __shfl_xor(oa[m], mm, 64);
    double bv = -1.0e300; int bi = 0x7fffffff;
#pragma unroll
    for (int m = 0; m < 7; m++) {
      if (m < nout) {
        double v = oa[m] + bod[m];
        if (v > bv) { bv = v; bi = wc0 + m; }  // ascending m: ties keep smaller idx
      }
    }
    if (c0 == 0) {
      __hip_atomic_store(&g_cval[slot * 5120 + b * 160 + bid], bv,
                         __ATOMIC_RELAXED, __HIP_MEMORY_SCOPE_AGENT);
      __hip_atomic_store(&g_cidx[slot * 5120 + b * 160 + bid], bi,
                         __ATOMIC_RELAXED, __HIP_MEMORY_SCOPE_AGENT);
    }
    __syncthreads();
    if (tid == 0) bump(F3L + (bid >> 4), F3R, 16u, step);

    // ================= decider: blocks 0..31 reduce row r=bid =====================
    if (bid < 32) {
      waitroot(F3R, (u32)(step + 1) * 10u);
      double v = -1.0e300; int ix = 0x7fffffff;
      if (tid < 160) {
        v = __hip_atomic_load(&g_cval[slot * 5120 + bid * 160 + tid],
                              __ATOMIC_RELAXED, __HIP_MEMORY_SCOPE_AGENT);
        ix = __hip_atomic_load(&g_cidx[slot * 5120 + bid * 160 + tid],
                               __ATOMIC_RELAXED, __HIP_MEMORY_SCOPE_AGENT);
      }
#pragma unroll
      for (int mm = 1; mm < 64; mm <<= 1) {
        double v2 = __shfl_xor(v, mm, 64);
        int i2 = __shfl_xor(ix, mm, 64);
        if (v2 > v || (v2 == v && i2 < ix)) { v = v2; ix = i2; }
      }
      if ((tid & 63) == 0) { s_dv[tid >> 6] = v; s_di[tid >> 6] = ix; }
      __syncthreads();
      if (tid == 0) {
        for (int w2 = 1; w2 < 8; w2++) {
          double v2 = s_dv[w2]; int i2 = s_di[w2];
          if (v2 > v || (v2 == v && i2 < ix)) { v = v2; ix = i2; }
        }
        if (scur == 0) alive = (tcur < lenr) ? 1 : 0;
        int em = (alive && ix != 1024) ? 1 : 0;
        out[(size_t)bid * 5000 + step] = (float)(em ? ix : 1024);
        if (em) lastr = ix;
        alive = em;
        __hip_atomic_store(&g_sym[slot * 32 + bid], (u32)(em | (lastr << 1)),
                           __ATOMIC_RELAXED, __HIP_MEMORY_SCOPE_AGENT);
        // RELEASE orders the g_sym store before the flag becomes visible
        u32 old = __hip_atomic_fetch_add(&g_cnt[(F4L + (bid >> 3)) * 32], 1u,
                                         __ATOMIC_RELEASE, __HIP_MEMORY_SCOPE_AGENT);
        if (old + 1u == (u32)(step + 1) * 8u)
          __hip_atomic_fetch_add(&g_cnt[F4R * 32], 1u, __ATOMIC_RELAXED, __HIP_MEMORY_SCOPE_AGENT);
      }
    }

    scur++;
    if (scur == 5) { scur = 0; tcur++; }
  }

  // final commit of step-4999 decision, then write cache_rnn_state
  waitroot(F4R, 5000u * 4u);
  {
    u32 w = 0;
    if ((tid & 15) == 0)
      w = __hip_atomic_load(&g_sym[1 * 32 + b], __ATOMIC_RELAXED, __HIP_MEMORY_SCOPE_AGENT);
    w = __shfl(w, (tid & 63) & 48, 64);
    if (w & 1u) { cst = cn_pend; hst = hn_pend; }
  }
  if (c0 < 4) {
    out[160000 + b * 640 + u0 + c0] = hst;
    out[160000 + 20480 + b * 640 + u0 + c0] = (float)cst;
  }
}

extern "C" void kernel_launch(void* const* d_in, const int* in_sizes, int n_in,
                              void* d_out, int out_size, void* d_ws, size_t ws_size,
                              hipStream_t stream) {
  const float* enc = (const float*)d_in[0];
  const int* lens = (const int*)d_in[1];
  const float* embed = (const float*)d_in[2];
  const float* Wx = (const float*)d_in[3];
  const float* Wh = (const float*)d_in[4];
  const float* b_lstm = (const float*)d_in[5];
  const float* Wenc = (const float*)d_in[6];
  const float* Wpred = (const float*)d_in[7];
  const float* b_joint = (const float*)d_in[8];
  const float* Wout = (const float*)d_in[9];
  const float* b_out = (const float*)d_in[10];
  float* out = (float*)d_out;
  (void)d_ws; (void)ws_size; (void)in_sizes; (void)n_in;

  hipLaunchKernelGGL(k_lut, dim3(1290), dim3(256), 0, stream, embed, Wx, b_lstm);
  hipLaunchKernelGGL(k_encproj, dim3(160, 32), dim3(256), 0, stream, enc, Wenc, b_joint);
  hipLaunchKernelGGL(k_tr, dim3(10563), dim3(256), 0, stream, Wh, Wpred, Wout);
  hipLaunchKernelGGL(k_decode, dim3(NB), dim3(TPB), 0, stream, out, lens, b_out);
}